// Round 1
// 1057.387 us; speedup vs baseline: 1.0071x; 1.0071x over previous
//
#include <hip/hip_runtime.h>

#define KN    32
#define DIN   128
#define TBL   2048   // dt-table resolution; entries TBL+1, linear interp err ~1e-7

// ---------------------------------------------------------------------------
// Kernel 1: fold W2@W4 -> u[128], W1@W4 -> v[128], and build the delta-time
// table: table[i] = b4 + sum_e W4[e] * sigmoid((i/TBL) * W3[e]).
// The t-term of the score depends on (n,k) only through scalar dt, so the
// whole 128-wide sigmoid reduction collapses to one interpolated lookup.
// ---------------------------------------------------------------------------
__global__ void precompute(const float* __restrict__ W1,
                           const float* __restrict__ W2,
                           const float* __restrict__ W3,
                           const float* __restrict__ W4,
                           const float* __restrict__ b4,
                           float* __restrict__ uv,      // u[128] ++ v[128]
                           float* __restrict__ table)   // [TBL+1]
{
    const int t = blockIdx.x * blockDim.x + threadIdx.x;
    if (blockIdx.x == 0) {
        const int tid = threadIdx.x;
        if (tid < DIN) {
            const float* row = W2 + tid * DIN;
            float acc = 0.f;
            for (int e = 0; e < DIN; ++e) acc += row[e] * W4[e];
            uv[tid] = acc;                       // u[d] = sum_e W2[d,e]*W4[e]
        } else {
            const int d = tid - DIN;
            const float* row = W1 + d * DIN;
            float acc = 0.f;
            for (int e = 0; e < DIN; ++e) acc += row[e] * W4[e];
            uv[DIN + d] = acc;                   // v[d] = sum_e W1[d,e]*W4[e]
        }
    }
    for (int i = t; i <= TBL; i += gridDim.x * blockDim.x) {
        const float x = (float)i * (1.0f / (float)TBL);
        float acc = b4[0];
        for (int e = 0; e < DIN; ++e)
            acc += W4[e] / (1.0f + __expf(-x * W3[e]));
        table[i] = acc;
    }
}

// ---------------------------------------------------------------------------
// Kernel 2: one block per n. Fully register-resident neigh tile:
//   thread t (g=t>>5, q=t&31) loads rows {g,g+8,g+16,g+24} at cols [4q,4q+4)
//   (the same perfectly-coalesced pattern as before, but kept in registers).
//   Score dot partials reduced via small padded LDS buffer; weighted sum
//   computed from the same registers and combined via an 8x128 LDS buffer.
//   No s_neigh, no per-(k,e) sigmoid.
// ---------------------------------------------------------------------------
__global__ __launch_bounds__(256) void attn_agg(
    const float* __restrict__ self_vecs,   // [N,128]
    const float* __restrict__ neigh_vecs,  // [N,32,128]
    const float* __restrict__ dt,          // [N,32]
    const float* __restrict__ uv,          // u[128] ++ v[128]
    const float* __restrict__ table,       // [TBL+1]
    float* __restrict__ out,               // [N,128]
    float* __restrict__ score_out)         // [N,32]
{
    __shared__ float s_p[KN * 33];                    // score partials [k][q], +1 pad
    __shared__ __align__(16) float s_part[8 * DIN];   // weighted partials [g][e]
    __shared__ float s_score[KN];
    __shared__ float s_qw4;

    const int n   = blockIdx.x;
    const int tid = threadIdx.x;
    const int g   = tid >> 5;     // 0..7
    const int q   = tid & 31;     // 0..31

    // ---- coalesced global loads straight into registers ----
    const float4* gsrc = (const float4*)(neigh_vecs + (size_t)n * KN * DIN);
    const float4 val0 = gsrc[tid];          // row g      , cols 4q..4q+3
    const float4 val1 = gsrc[tid + 256];    // row g + 8
    const float4 val2 = gsrc[tid + 512];    // row g + 16
    const float4 val3 = gsrc[tid + 768];    // row g + 24
    const float4 u4   = *(const float4*)(uv + 4 * q);  // L1-hot

    // ---- qW4 = self[n] . v  (wave 0, overlapped with other waves' loads) ----
    if (tid < 64) {
        const float* v  = uv + DIN;
        const float* sv = self_vecs + (size_t)n * DIN;
        float qp = sv[tid] * v[tid] + sv[tid + 64] * v[tid + 64];
        #pragma unroll
        for (int off = 32; off > 0; off >>= 1)
            qp += __shfl_down(qp, off, 64);
        if (tid == 0) s_qw4 = qp;
    }

    // ---- score dot partials: s_p[k][q] = dot4(neigh[k,4q..4q+3], u[4q..4q+3]) ----
    s_p[ g       * 33 + q] = val0.x*u4.x + val0.y*u4.y + val0.z*u4.z + val0.w*u4.w;
    s_p[(g +  8) * 33 + q] = val1.x*u4.x + val1.y*u4.y + val1.z*u4.z + val1.w*u4.w;
    s_p[(g + 16) * 33 + q] = val2.x*u4.x + val2.y*u4.y + val2.z*u4.z + val2.w*u4.w;
    s_p[(g + 24) * 33 + q] = val3.x*u4.x + val3.y*u4.y + val3.z*u4.z + val3.w*u4.w;
    __syncthreads();

    // ---- scores + softmax (wave 0: 2 lanes per k reduce 32 partials) ----
    if (tid < 64) {
        const int k = tid & 31;
        const int h = tid >> 5;
        const float* pr = s_p + k * 33 + h * 16;   // banks (k+16h+j)%32: 2-way, free
        float s = 0.f;
        #pragma unroll
        for (int j = 0; j < 16; ++j) s += pr[j];
        s += __shfl_down(s, 32, 64);               // lanes<32 now hold full dot_k
        if (tid < 32) {
            const float dtk = dt[(size_t)n * KN + k];
            float fx = fminf(fmaxf(dtk, 0.0f), 1.0f) * (float)TBL;
            int   i0 = min((int)fx, TBL - 1);
            const float fr = fx - (float)i0;
            const float t0 = table[i0];
            const float t1 = table[i0 + 1];
            float sp = s_qw4 + s + t0 + fr * (t1 - t0);   // b4 folded into table
            sp = sp > 0.f ? sp : 0.f;
            // softmax over the 32 k-lanes
            float mx = sp;
            #pragma unroll
            for (int off = 16; off > 0; off >>= 1)
                mx = fmaxf(mx, __shfl_xor(mx, off, 32));
            const float ex = __expf(sp - mx);
            float sm = ex;
            #pragma unroll
            for (int off = 16; off > 0; off >>= 1)
                sm += __shfl_xor(sm, off, 32);
            const float sc = ex / sm;
            s_score[k] = sc;
            score_out[(size_t)n * KN + k] = sc;
        }
    }
    __syncthreads();

    // ---- weighted sum from registers: po = sum_i score[g+8i] * val_i ----
    {
        const float sc0 = s_score[g];        // uniform per half-wave: broadcast
        const float sc1 = s_score[g + 8];
        const float sc2 = s_score[g + 16];
        const float sc3 = s_score[g + 24];
        float4 po;
        po.x = sc0*val0.x + sc1*val1.x + sc2*val2.x + sc3*val3.x;
        po.y = sc0*val0.y + sc1*val1.y + sc2*val2.y + sc3*val3.y;
        po.z = sc0*val0.z + sc1*val1.z + sc2*val2.z + sc3*val3.z;
        po.w = sc0*val0.w + sc1*val1.w + sc2*val2.w + sc3*val3.w;
        *(float4*)(s_part + g * DIN + 4 * q) = po;
    }
    __syncthreads();

    // ---- combine the 8 g-partials and store (columns e%32: 2-way, free) ----
    if (tid < DIN) {
        float acc = 0.f;
        #pragma unroll
        for (int gg = 0; gg < 8; ++gg) acc += s_part[gg * DIN + tid];
        out[(size_t)n * DIN + tid] = acc;
    }
}

// ---------------------------------------------------------------------------
extern "C" void kernel_launch(void* const* d_in, const int* in_sizes, int n_in,
                              void* d_out, int out_size, void* d_ws, size_t ws_size,
                              hipStream_t stream) {
    const float* self_vecs = (const float*)d_in[0];
    const float* neigh     = (const float*)d_in[1];
    const float* dtim      = (const float*)d_in[2];
    const float* W1        = (const float*)d_in[3];
    const float* W2        = (const float*)d_in[4];
    const float* W3        = (const float*)d_in[5];
    const float* W4        = (const float*)d_in[6];
    const float* b4        = (const float*)d_in[7];

    const int N = in_sizes[0] / DIN;           // 50000
    float* uv    = (float*)d_ws;               // 256 floats
    float* table = uv + 256;                   // TBL+1 floats
    float* out       = (float*)d_out;          // [N,128]
    float* score_out = out + (size_t)N * DIN;  // [N,32]

    precompute<<<9, 256, 0, stream>>>(W1, W2, W3, W4, b4, uv, table);
    attn_agg<<<N, 256, 0, stream>>>(self_vecs, neigh, dtim, uv, table,
                                    out, score_out);
}